// Round 1
// baseline (144.336 us; speedup 1.0000x reference)
//
#include <hip/hip_runtime.h>
#include <hip/hip_bf16.h>

#define A_N 8192
#define F_N 16
#define NCHUNK 16
#define JC 512
#define TJ 256

// ---------------- K1: conv 2x2 (pad 1) + relu + quadrant mean-pool ----------------
// block = (m, ch, a, b) ; bid = ((m*16+ch)*2+a)*2+b ; output sf[bid]
__global__ __launch_bounds__(256) void conv_pool(
    const float* __restrict__ x, const float* __restrict__ cw,
    const float* __restrict__ cb, float* __restrict__ sf) {
  int bid = blockIdx.x;
  int b  = bid & 1;
  int a  = (bid >> 1) & 1;
  int ch = (bid >> 2) & 15;
  int m  = bid >> 6;
  float w00 = cw[ch*4+0], w01 = cw[ch*4+1], w10 = cw[ch*4+2], w11 = cw[ch*4+3];
  float bias = cb[ch];
  const float* xm = x + (size_t)m * 255 * 255;
  int tid = threadIdx.x;
  float sum = 0.f;
  for (int p = tid; p < 16384; p += 256) {
    int i = a*128 + (p >> 7);
    int j = b*128 + (p & 127);
    float x00 = (i >= 1 && j >= 1)   ? xm[(i-1)*255 + (j-1)] : 0.f;
    float x01 = (i >= 1 && j <= 254) ? xm[(i-1)*255 + j]     : 0.f;
    float x10 = (i <= 254 && j >= 1) ? xm[i*255 + (j-1)]     : 0.f;
    float x11 = (i <= 254 && j <= 254) ? xm[i*255 + j]       : 0.f;
    float v = fmaf(x00,w00, fmaf(x01,w01, fmaf(x10,w10, fmaf(x11,w11, bias))));
    sum += fmaxf(v, 0.f);
  }
  for (int o = 32; o; o >>= 1) sum += __shfl_down(sum, o, 64);
  __shared__ float red[4];
  int wid = tid >> 6, lane = tid & 63;
  if (lane == 0) red[wid] = sum;
  __syncthreads();
  if (tid == 0) sf[bid] = (red[0]+red[1]+red[2]+red[3]) * (1.0f/16384.0f);
}

// ---------------- K2: gather + Q,K,V and V2 = V@wo --------------------------------
// Q stored pre-scaled by 0.25 (= 1/sqrt(F))
__global__ __launch_bounds__(256) void qkv_kernel(
    const int* __restrict__ act, const float* __restrict__ feat,
    const float* __restrict__ wq, const float* __restrict__ bq,
    const float* __restrict__ wk, const float* __restrict__ bk,
    const float* __restrict__ wv, const float* __restrict__ bv,
    const float* __restrict__ wo,
    float* __restrict__ Qo, float* __restrict__ Ko, float* __restrict__ V2o) {
  __shared__ float swq[256], swk[256], swv[256], swo[256];
  __shared__ float sbq[16], sbk[16], sbv[16];
  int tid = threadIdx.x;
  swq[tid] = wq[tid]; swk[tid] = wk[tid]; swv[tid] = wv[tid]; swo[tid] = wo[tid];
  if (tid < 16) { sbq[tid] = bq[tid]; sbk[tid] = bk[tid]; sbv[tid] = bv[tid]; }
  __syncthreads();
  int row = blockIdx.x * 256 + tid;
  int idx = act[row];
  const float4* f4 = (const float4*)(feat + (size_t)idx * 16);
  float4 a0 = f4[0], a1 = f4[1], a2 = f4[2], a3 = f4[3];
  float af[16] = {a0.x,a0.y,a0.z,a0.w, a1.x,a1.y,a1.z,a1.w,
                  a2.x,a2.y,a2.z,a2.w, a3.x,a3.y,a3.z,a3.w};
  float q[16], k[16], v[16], v2[16];
  #pragma unroll
  for (int kk = 0; kk < 16; ++kk) {
    float aq = sbq[kk], ak = sbk[kk], av = sbv[kk];
    #pragma unroll
    for (int f = 0; f < 16; ++f) {
      aq = fmaf(af[f], swq[f*16+kk], aq);
      ak = fmaf(af[f], swk[f*16+kk], ak);
      av = fmaf(af[f], swv[f*16+kk], av);
    }
    q[kk] = aq; k[kk] = ak; v[kk] = av;
  }
  #pragma unroll
  for (int kk = 0; kk < 16; ++kk) {
    float a = 0.f;
    #pragma unroll
    for (int f = 0; f < 16; ++f) a = fmaf(v[f], swo[f*16+kk], a);
    v2[kk] = a;
  }
  float* qd = Qo + (size_t)row*16;
  float* kd = Ko + (size_t)row*16;
  float* vd = V2o + (size_t)row*16;
  #pragma unroll
  for (int f = 0; f < 16; ++f) { qd[f] = q[f]*0.25f; kd[f] = k[f]; vd[f] = v2[f]; }
}

// ---------------- K3: cvec[k] = b1 + st@W1_top + bo@W1_mid ------------------------
__global__ void cvec_kernel(const float* __restrict__ sf, const float* __restrict__ w1,
                            const float* __restrict__ b1, const float* __restrict__ bo,
                            float* __restrict__ cvec) {
  int k = threadIdx.x;
  if (k >= 16) return;
  float c = b1[k];
  for (int s = 0; s < 192; ++s) c = fmaf(sf[s], w1[s*16+k], c);
  for (int f = 0; f < 16; ++f)  c = fmaf(bo[f], w1[(192+f)*16+k], c);
  cvec[k] = c;
}

// ---------------- K4: flash attention partials (no-max; energies bounded) ---------
__global__ __launch_bounds__(256) void attn_partial(
    const float* __restrict__ Q, const float* __restrict__ Kg,
    const float* __restrict__ V2, float* __restrict__ part) {
  __shared__ float4 sK[TJ][4];
  __shared__ float4 sV[TJ][4];
  int tid = threadIdx.x;
  int rb = blockIdx.x / NCHUNK;
  int chunk = blockIdx.x - rb * NCHUNK;
  int row = rb * 256 + tid;
  const float4* q4 = (const float4*)(Q + (size_t)row * 16);
  float4 q0 = q4[0], q1 = q4[1], q2 = q4[2], q3 = q4[3];
  float l = 0.f;
  float acc[16];
  #pragma unroll
  for (int f = 0; f < 16; ++f) acc[f] = 0.f;
  for (int t = 0; t < JC / TJ; ++t) {
    int j0 = chunk * JC + t * TJ;
    __syncthreads();
    {
      const float4* kg = (const float4*)(Kg + (size_t)(j0 + tid) * 16);
      sK[tid][0] = kg[0]; sK[tid][1] = kg[1]; sK[tid][2] = kg[2]; sK[tid][3] = kg[3];
      const float4* vg = (const float4*)(V2 + (size_t)(j0 + tid) * 16);
      sV[tid][0] = vg[0]; sV[tid][1] = vg[1]; sV[tid][2] = vg[2]; sV[tid][3] = vg[3];
    }
    __syncthreads();
    #pragma unroll 2
    for (int j = 0; j < TJ; ++j) {
      float4 k0 = sK[j][0], k1 = sK[j][1], k2 = sK[j][2], k3 = sK[j][3];
      float e = q0.x * k0.x;
      e = fmaf(q0.y,k0.y,e); e = fmaf(q0.z,k0.z,e); e = fmaf(q0.w,k0.w,e);
      e = fmaf(q1.x,k1.x,e); e = fmaf(q1.y,k1.y,e); e = fmaf(q1.z,k1.z,e); e = fmaf(q1.w,k1.w,e);
      e = fmaf(q2.x,k2.x,e); e = fmaf(q2.y,k2.y,e); e = fmaf(q2.z,k2.z,e); e = fmaf(q2.w,k2.w,e);
      e = fmaf(q3.x,k3.x,e); e = fmaf(q3.y,k3.y,e); e = fmaf(q3.z,k3.z,e); e = fmaf(q3.w,k3.w,e);
      float p = __expf(e);
      l += p;
      float4 v0 = sV[j][0], v1 = sV[j][1], v2v = sV[j][2], v3 = sV[j][3];
      acc[0]  = fmaf(p, v0.x, acc[0]);  acc[1]  = fmaf(p, v0.y, acc[1]);
      acc[2]  = fmaf(p, v0.z, acc[2]);  acc[3]  = fmaf(p, v0.w, acc[3]);
      acc[4]  = fmaf(p, v1.x, acc[4]);  acc[5]  = fmaf(p, v1.y, acc[5]);
      acc[6]  = fmaf(p, v1.z, acc[6]);  acc[7]  = fmaf(p, v1.w, acc[7]);
      acc[8]  = fmaf(p, v2v.x, acc[8]); acc[9]  = fmaf(p, v2v.y, acc[9]);
      acc[10] = fmaf(p, v2v.z, acc[10]);acc[11] = fmaf(p, v2v.w, acc[11]);
      acc[12] = fmaf(p, v3.x, acc[12]); acc[13] = fmaf(p, v3.y, acc[13]);
      acc[14] = fmaf(p, v3.z, acc[14]); acc[15] = fmaf(p, v3.w, acc[15]);
    }
  }
  float* dst = part + (size_t)(row * NCHUNK + chunk) * 17;
  dst[0] = l;
  #pragma unroll
  for (int f = 0; f < 16; ++f) dst[1+f] = acc[f];
}

// ---------------- K5: reduce partials + fused MLP scoring -------------------------
__global__ __launch_bounds__(256) void reduce_score(
    const float* __restrict__ part, const float* __restrict__ w1,
    const float* __restrict__ cvec, const float* __restrict__ w2,
    float* __restrict__ scores) {
  __shared__ float sw1[256];  // W1 rows 192..207 (the `out` part)
  __shared__ float sc[16], sw2[16];
  int tid = threadIdx.x;
  sw1[tid] = w1[192*16 + tid];
  if (tid < 16) { sc[tid] = cvec[tid]; sw2[tid] = w2[tid]; }
  __syncthreads();
  int row = blockIdx.x * 256 + tid;
  const float* p = part + (size_t)row * NCHUNK * 17;
  float l = 0.f;
  float acc[16];
  #pragma unroll
  for (int f = 0; f < 16; ++f) acc[f] = 0.f;
  for (int c = 0; c < NCHUNK; ++c) {
    const float* pc = p + c * 17;
    l += pc[0];
    #pragma unroll
    for (int f = 0; f < 16; ++f) acc[f] += pc[1+f];
  }
  float inv = 1.0f / l;
  float score = 0.f;
  #pragma unroll
  for (int k = 0; k < 16; ++k) {
    float h = sc[k];
    #pragma unroll
    for (int f = 0; f < 16; ++f) h = fmaf(acc[f]*inv, sw1[f*16+k], h);
    h = fmaxf(h, 0.f);
    score = fmaf(h, sw2[k], score);
  }
  scores[row] = score;
}

// ---------------- K6: softmax over the 8192 scores --------------------------------
__global__ __launch_bounds__(1024) void softmax_final(
    const float* __restrict__ scores, float* __restrict__ out) {
  __shared__ float red[16];
  __shared__ float sbc[2];
  int tid = threadIdx.x;
  int lane = tid & 63, wid = tid >> 6;
  float m = -3.4e38f;
  for (int i = tid; i < A_N; i += 1024) m = fmaxf(m, scores[i]);
  for (int o = 32; o; o >>= 1) m = fmaxf(m, __shfl_down(m, o, 64));
  if (lane == 0) red[wid] = m;
  __syncthreads();
  if (tid == 0) {
    float mm = red[0];
    for (int w = 1; w < 16; ++w) mm = fmaxf(mm, red[w]);
    sbc[0] = mm;
  }
  __syncthreads();
  float mx = sbc[0];
  float s = 0.f;
  for (int i = tid; i < A_N; i += 1024) s += __expf(scores[i] - mx);
  for (int o = 32; o; o >>= 1) s += __shfl_down(s, o, 64);
  if (lane == 0) red[wid] = s;
  __syncthreads();
  if (tid == 0) {
    float ss = 0.f;
    for (int w = 0; w < 16; ++w) ss += red[w];
    sbc[1] = ss;
  }
  __syncthreads();
  float inv = 1.0f / sbc[1];
  for (int i = tid; i < A_N; i += 1024) out[i] = __expf(scores[i] - mx) * inv;
}

extern "C" void kernel_launch(void* const* d_in, const int* in_sizes, int n_in,
                              void* d_out, int out_size, void* d_ws, size_t ws_size,
                              hipStream_t stream) {
  const float* x      = (const float*)d_in[0];
  const int*   act    = (const int*)  d_in[1];
  const float* feat   = (const float*)d_in[2];
  const float* conv_w = (const float*)d_in[3];
  const float* conv_b = (const float*)d_in[4];
  const float* wq     = (const float*)d_in[5];
  const float* bq     = (const float*)d_in[6];
  const float* wk     = (const float*)d_in[7];
  const float* bk     = (const float*)d_in[8];
  const float* wv     = (const float*)d_in[9];
  const float* bv     = (const float*)d_in[10];
  const float* wo     = (const float*)d_in[11];
  const float* bo     = (const float*)d_in[12];
  const float* w1     = (const float*)d_in[13];
  const float* b1     = (const float*)d_in[14];
  const float* w2     = (const float*)d_in[15];
  // d_in[16] = mlp_b2: softmax is shift-invariant, dropped.

  float* ws     = (float*)d_ws;
  float* sf     = ws + 0;        // 192
  float* cvec   = ws + 256;      // 16
  float* scores = ws + 512;      // 8192
  float* Qb     = ws + 16384;    // 8192*16
  float* Kb     = ws + 147456;   // 8192*16
  float* V2b    = ws + 278528;   // 8192*16
  float* part   = ws + 409600;   // 8192*16*17
  float* out    = (float*)d_out;

  conv_pool   <<<192, 256, 0, stream>>>(x, conv_w, conv_b, sf);
  qkv_kernel  <<<A_N/256, 256, 0, stream>>>(act, feat, wq, bq, wk, bk, wv, bv, wo, Qb, Kb, V2b);
  cvec_kernel <<<1, 64, 0, stream>>>(sf, w1, b1, bo, cvec);
  attn_partial<<<(A_N/256)*NCHUNK, 256, 0, stream>>>(Qb, Kb, V2b, part);
  reduce_score<<<A_N/256, 256, 0, stream>>>(part, w1, cvec, w2, scores);
  softmax_final<<<1, 1024, 0, stream>>>(scores, out);
}

// Round 2
// 77.428 us; speedup vs baseline: 1.8641x; 1.8641x over previous
//
#include <hip/hip_runtime.h>
#include <hip/hip_bf16.h>

#define A_N 8192
#define LOG2E 1.44269504f

typedef __attribute__((ext_vector_type(8))) short short8v;
typedef __attribute__((ext_vector_type(4))) float f32x4;
typedef __attribute__((ext_vector_type(4))) int   i32x4;

__device__ inline short f2bf(float x) {
  unsigned u = __builtin_bit_cast(unsigned, x);
  unsigned r = (u + 0x7FFFu + ((u >> 16) & 1u)) >> 16;
  return (short)r;
}
__device__ inline float fexp2(float x) {
  float r; asm("v_exp_f32 %0, %1" : "=v"(r) : "v"(x)); return r;
}
__device__ inline unsigned cvtpk(float lo, float hi) {
  unsigned r; asm("v_cvt_pk_bf16_f32 %0, %1, %2" : "=v"(r) : "v"(lo), "v"(hi)); return r;
}

// ---------------- K1: conv 2x2 (pad 1) + relu + quadrant mean-pool ----------------
__global__ __launch_bounds__(256) void conv_pool(
    const float* __restrict__ x, const float* __restrict__ cw,
    const float* __restrict__ cb, float* __restrict__ sf) {
  int bid = blockIdx.x;
  int b  = bid & 1;
  int a  = (bid >> 1) & 1;
  int ch = (bid >> 2) & 15;
  int m  = bid >> 6;
  float w00 = cw[ch*4+0], w01 = cw[ch*4+1], w10 = cw[ch*4+2], w11 = cw[ch*4+3];
  float bias = cb[ch];
  const float* xm = x + (size_t)m * 255 * 255;
  int tid = threadIdx.x;
  float sum = 0.f;
  for (int p = tid; p < 16384; p += 256) {
    int i = a*128 + (p >> 7);
    int j = b*128 + (p & 127);
    float x00 = (i >= 1 && j >= 1)   ? xm[(i-1)*255 + (j-1)] : 0.f;
    float x01 = (i >= 1 && j <= 254) ? xm[(i-1)*255 + j]     : 0.f;
    float x10 = (i <= 254 && j >= 1) ? xm[i*255 + (j-1)]     : 0.f;
    float x11 = (i <= 254 && j <= 254) ? xm[i*255 + j]       : 0.f;
    float v = fmaf(x00,w00, fmaf(x01,w01, fmaf(x10,w10, fmaf(x11,w11, bias))));
    sum += fmaxf(v, 0.f);
  }
  for (int o = 32; o; o >>= 1) sum += __shfl_down(sum, o, 64);
  __shared__ float red[4];
  int wid = tid >> 6, lane = tid & 63;
  if (lane == 0) red[wid] = sum;
  __syncthreads();
  if (tid == 0) sf[bid] = (red[0]+red[1]+red[2]+red[3]) * (1.0f/16384.0f);
}

// ---------------- K2: gather + Q,K (bf16) and V2T = (V@wo)^T (bf16) ---------------
// Q pre-scaled by 0.25 * log2(e)  (so attention exp uses v_exp_f32 directly)
__global__ __launch_bounds__(256) void qkv_kernel(
    const int* __restrict__ act, const float* __restrict__ feat,
    const float* __restrict__ wq, const float* __restrict__ bq,
    const float* __restrict__ wk, const float* __restrict__ bk,
    const float* __restrict__ wv, const float* __restrict__ bv,
    const float* __restrict__ wo,
    short* __restrict__ Qo, short* __restrict__ Ko, short* __restrict__ V2T) {
  __shared__ float swq[256], swk[256], swv[256], swo[256];
  __shared__ float sbq[16], sbk[16], sbv[16];
  int tid = threadIdx.x;
  swq[tid] = wq[tid]; swk[tid] = wk[tid]; swv[tid] = wv[tid]; swo[tid] = wo[tid];
  if (tid < 16) { sbq[tid] = bq[tid]; sbk[tid] = bk[tid]; sbv[tid] = bv[tid]; }
  __syncthreads();
  int row = blockIdx.x * 256 + tid;
  int idx = act[row];
  const float4* f4 = (const float4*)(feat + (size_t)idx * 16);
  float4 a0 = f4[0], a1 = f4[1], a2 = f4[2], a3 = f4[3];
  float af[16] = {a0.x,a0.y,a0.z,a0.w, a1.x,a1.y,a1.z,a1.w,
                  a2.x,a2.y,a2.z,a2.w, a3.x,a3.y,a3.z,a3.w};
  float q[16], k[16], v[16];
  #pragma unroll
  for (int kk = 0; kk < 16; ++kk) {
    float aq = sbq[kk], ak = sbk[kk], av = sbv[kk];
    #pragma unroll
    for (int f = 0; f < 16; ++f) {
      aq = fmaf(af[f], swq[f*16+kk], aq);
      ak = fmaf(af[f], swk[f*16+kk], ak);
      av = fmaf(af[f], swv[f*16+kk], av);
    }
    q[kk] = aq; k[kk] = ak; v[kk] = av;
  }
  const float qs = 0.25f * LOG2E;
  #pragma unroll
  for (int kk = 0; kk < 16; ++kk) {
    float a = 0.f;
    #pragma unroll
    for (int f = 0; f < 16; ++f) a = fmaf(v[f], swo[f*16+kk], a);
    V2T[(size_t)kk * A_N + row] = f2bf(a);
    Qo[(size_t)row*16 + kk] = f2bf(q[kk] * qs);
    Ko[(size_t)row*16 + kk] = f2bf(k[kk]);
  }
}

// ---------------- K3: cvec[k] = b1 + st@W1_top + bo@W1_mid ------------------------
__global__ void cvec_kernel(const float* __restrict__ sf, const float* __restrict__ w1,
                            const float* __restrict__ b1, const float* __restrict__ bo,
                            float* __restrict__ cvec) {
  int k = threadIdx.x;
  if (k >= 16) return;
  float c = b1[k];
  for (int s = 0; s < 192; ++s) c = fmaf(sf[s], w1[s*16+k], c);
  for (int f = 0; f < 16; ++f)  c = fmaf(bo[f], w1[(192+f)*16+k], c);
  cvec[k] = c;
}

// ---------------- K4: MFMA flash attention + fused MLP scoring --------------------
// Block = one 16-row Q tile; 4 waves = 4 j-quarters (2048 j each, 64 steps of 32 j).
// QK^T: mfma(Ktile, Qtile) -> lane holds E[j=4g+r][i=lane&15]; exp2 -> P already in
// PV A-fragment layout (with matching k-permutation on V2T side). No shuffles.
__global__ __launch_bounds__(256) void attn_score(
    const short* __restrict__ Qb, const short* __restrict__ Kb,
    const short* __restrict__ V2T, const float* __restrict__ cvec,
    const float* __restrict__ w1, const float* __restrict__ w2,
    float* __restrict__ scores) {
  __shared__ float sacc[4][16][16];
  __shared__ float sl[4][16];
  __shared__ float sw1[256];
  __shared__ float scv[16], sw2s[16];
  int tid = threadIdx.x;
  sw1[tid] = w1[192*16 + tid];
  if (tid < 16) { scv[tid] = cvec[tid]; sw2s[tid] = w2[tid]; }
  int w = tid >> 6, lane = tid & 63;
  int g = lane >> 4, fi = lane & 15;
  int i0 = blockIdx.x * 16;

  short8v z8 = {};
  short8v qf = z8;
  if (g < 2) qf = *(const short8v*)(Qb + (size_t)(i0 + fi)*16 + g*8);
  const short* kp = Kb + (size_t)(w*2048 + fi)*16 + g*8;
  const short* vp = V2T + (size_t)fi*A_N + w*2048 + g*4;

  f32x4 acc = {0.f,0.f,0.f,0.f};
  float lsum = 0.f;
  #pragma unroll 2
  for (int step = 0; step < 64; ++step) {
    short8v kf0 = z8, kf1 = z8;
    if (g < 2) {
      kf0 = *(const short8v*)(kp);
      kf1 = *(const short8v*)(kp + 256);   // +16 rows
    }
    f32x4 zero4 = {0.f,0.f,0.f,0.f};
    f32x4 e0 = __builtin_amdgcn_mfma_f32_16x16x32_bf16(kf0, qf, zero4, 0, 0, 0);
    f32x4 e1 = __builtin_amdgcn_mfma_f32_16x16x32_bf16(kf1, qf, zero4, 0, 0, 0);
    float p00 = fexp2(e0[0]), p01 = fexp2(e0[1]), p02 = fexp2(e0[2]), p03 = fexp2(e0[3]);
    float p10 = fexp2(e1[0]), p11 = fexp2(e1[1]), p12 = fexp2(e1[2]), p13 = fexp2(e1[3]);
    lsum += ((p00+p01)+(p02+p03)) + ((p10+p11)+(p12+p13));
    i32x4 pk;
    pk[0] = cvtpk(p00, p01); pk[1] = cvtpk(p02, p03);
    pk[2] = cvtpk(p10, p11); pk[3] = cvtpk(p12, p13);
    short8v pa = __builtin_bit_cast(short8v, pk);
    int2 va = *(const int2*)(vp);
    int2 vb = *(const int2*)(vp + 16);   // +16 j
    i32x4 vv; vv[0] = va.x; vv[1] = va.y; vv[2] = vb.x; vv[3] = vb.y;
    short8v vf = __builtin_bit_cast(short8v, vv);
    acc = __builtin_amdgcn_mfma_f32_16x16x32_bf16(pa, vf, acc, 0, 0, 0);
    kp += 512;  // 32 rows * 16
    vp += 32;   // 32 j
  }
  lsum += __shfl_xor(lsum, 16, 64);
  lsum += __shfl_xor(lsum, 32, 64);
  #pragma unroll
  for (int r = 0; r < 4; ++r) sacc[w][4*g + r][fi] = acc[r];
  if (g == 0) sl[w][fi] = lsum;
  __syncthreads();
  {
    int i = tid >> 4, f = tid & 15;
    float o = sacc[0][i][f] + sacc[1][i][f] + sacc[2][i][f] + sacc[3][i][f];
    float li = sl[0][i] + sl[1][i] + sl[2][i] + sl[3][i];
    sacc[0][i][f] = o / li;
  }
  __syncthreads();
  {
    int i = tid >> 4, k = tid & 15;
    float h = scv[k];
    #pragma unroll
    for (int f = 0; f < 16; ++f) h = fmaf(sacc[0][i][f], sw1[f*16+k], h);
    h = fmaxf(h, 0.f);
    float t = h * sw2s[k];
    t += __shfl_xor(t, 1, 64);
    t += __shfl_xor(t, 2, 64);
    t += __shfl_xor(t, 4, 64);
    t += __shfl_xor(t, 8, 64);
    if (k == 0) scores[i0 + i] = t;
  }
}

// ---------------- K5: softmax over the 8192 scores --------------------------------
__global__ __launch_bounds__(1024) void softmax_final(
    const float* __restrict__ scores, float* __restrict__ out) {
  __shared__ float red[16];
  __shared__ float sbc[2];
  int tid = threadIdx.x;
  int lane = tid & 63, wid = tid >> 6;
  float m = -3.4e38f;
  for (int i = tid; i < A_N; i += 1024) m = fmaxf(m, scores[i]);
  for (int o = 32; o; o >>= 1) m = fmaxf(m, __shfl_down(m, o, 64));
  if (lane == 0) red[wid] = m;
  __syncthreads();
  if (tid == 0) {
    float mm = red[0];
    for (int w = 1; w < 16; ++w) mm = fmaxf(mm, red[w]);
    sbc[0] = mm;
  }
  __syncthreads();
  float mx = sbc[0];
  float s = 0.f;
  for (int i = tid; i < A_N; i += 1024) s += __expf(scores[i] - mx);
  for (int o = 32; o; o >>= 1) s += __shfl_down(s, o, 64);
  if (lane == 0) red[wid] = s;
  __syncthreads();
  if (tid == 0) {
    float ss = 0.f;
    for (int w = 0; w < 16; ++w) ss += red[w];
    sbc[1] = ss;
  }
  __syncthreads();
  float inv = 1.0f / sbc[1];
  for (int i = tid; i < A_N; i += 1024) out[i] = __expf(scores[i] - mx) * inv;
}

extern "C" void kernel_launch(void* const* d_in, const int* in_sizes, int n_in,
                              void* d_out, int out_size, void* d_ws, size_t ws_size,
                              hipStream_t stream) {
  const float* x      = (const float*)d_in[0];
  const int*   act    = (const int*)  d_in[1];
  const float* feat   = (const float*)d_in[2];
  const float* conv_w = (const float*)d_in[3];
  const float* conv_b = (const float*)d_in[4];
  const float* wq     = (const float*)d_in[5];
  const float* bq     = (const float*)d_in[6];
  const float* wk     = (const float*)d_in[7];
  const float* bk     = (const float*)d_in[8];
  const float* wv     = (const float*)d_in[9];
  const float* bv     = (const float*)d_in[10];
  const float* wo     = (const float*)d_in[11];
  const float* bo     = (const float*)d_in[12];
  const float* w1     = (const float*)d_in[13];
  const float* b1     = (const float*)d_in[14];
  const float* w2     = (const float*)d_in[15];
  // d_in[16] = mlp_b2: softmax shift-invariant, dropped.

  char* wsb = (char*)d_ws;
  float* sf     = (float*)(wsb);             // 192 floats
  float* cvec   = (float*)(wsb + 1024);      // 16
  float* scores = (float*)(wsb + 2048);      // 8192
  short* Qb     = (short*)(wsb + 65536);             // 8192*16 bf16
  short* Kb     = (short*)(wsb + 65536 + 262144);    // 8192*16 bf16
  short* V2T    = (short*)(wsb + 65536 + 524288);    // 16*8192 bf16
  float* out    = (float*)d_out;

  conv_pool    <<<192, 256, 0, stream>>>(x, conv_w, conv_b, sf);
  qkv_kernel   <<<A_N/256, 256, 0, stream>>>(act, feat, wq, bq, wk, bk, wv, bv, wo, Qb, Kb, V2T);
  cvec_kernel  <<<1, 64, 0, stream>>>(sf, w1, b1, bo, cvec);
  attn_score   <<<A_N/16, 256, 0, stream>>>(Qb, Kb, V2T, cvec, w1, w2, scores);
  softmax_final<<<1, 1024, 0, stream>>>(scores, out);
}

// Round 6
// 71.053 us; speedup vs baseline: 2.0314x; 1.0897x over previous
//
#include <hip/hip_runtime.h>
#include <hip/hip_bf16.h>

#define A_N 8192
#define LOG2E 1.44269504f

typedef __attribute__((ext_vector_type(8))) short short8v;
typedef __attribute__((ext_vector_type(4))) float f32x4;
typedef __attribute__((ext_vector_type(4))) int   i32x4;

__device__ inline short f2bf(float x) {
  unsigned u = __builtin_bit_cast(unsigned, x);
  unsigned r = (u + 0x7FFFu + ((u >> 16) & 1u)) >> 16;
  return (short)r;
}
__device__ inline float fexp2(float x) {
  float r; asm("v_exp_f32 %0, %1" : "=v"(r) : "v"(x)); return r;
}
__device__ inline unsigned cvtpk(float lo, float hi) {
  unsigned r; asm("v_cvt_pk_bf16_f32 %0, %1, %2" : "=v"(r) : "v"(lo), "v"(hi)); return r;
}

// ---------------- K1: fused conv_pool (blocks 0..191) + qkv (blocks 192..223) -----
// Both bodies are R2-verbatim; disjoint block ranges, disjoint outputs.
__global__ __launch_bounds__(256) void fused_pre(
    const float* __restrict__ x, const float* __restrict__ cw,
    const float* __restrict__ cb, float* __restrict__ sf,
    const int* __restrict__ act, const float* __restrict__ feat,
    const float* __restrict__ wq, const float* __restrict__ bq,
    const float* __restrict__ wk, const float* __restrict__ bk,
    const float* __restrict__ wv, const float* __restrict__ bv,
    const float* __restrict__ wo,
    short* __restrict__ Qo, short* __restrict__ Ko, short* __restrict__ V2T) {
  __shared__ float swq[256], swk[256], swv[256], swo[256];
  __shared__ float sbq[16], sbk[16], sbv[16];
  __shared__ float red[4];
  int tid = threadIdx.x;
  if (blockIdx.x < 192) {
    // ---- conv_pool body (R2-verbatim) ----
    int bid = blockIdx.x;
    int b  = bid & 1;
    int a  = (bid >> 1) & 1;
    int ch = (bid >> 2) & 15;
    int m  = bid >> 6;
    float w00 = cw[ch*4+0], w01 = cw[ch*4+1], w10 = cw[ch*4+2], w11 = cw[ch*4+3];
    float bias = cb[ch];
    const float* xm = x + (size_t)m * 255 * 255;
    float sum = 0.f;
    for (int p = tid; p < 16384; p += 256) {
      int i = a*128 + (p >> 7);
      int j = b*128 + (p & 127);
      float x00 = (i >= 1 && j >= 1)   ? xm[(i-1)*255 + (j-1)] : 0.f;
      float x01 = (i >= 1 && j <= 254) ? xm[(i-1)*255 + j]     : 0.f;
      float x10 = (i <= 254 && j >= 1) ? xm[i*255 + (j-1)]     : 0.f;
      float x11 = (i <= 254 && j <= 254) ? xm[i*255 + j]       : 0.f;
      float v = fmaf(x00,w00, fmaf(x01,w01, fmaf(x10,w10, fmaf(x11,w11, bias))));
      sum += fmaxf(v, 0.f);
    }
    for (int o = 32; o; o >>= 1) sum += __shfl_down(sum, o, 64);
    int wid = tid >> 6, lane = tid & 63;
    if (lane == 0) red[wid] = sum;
    __syncthreads();
    if (tid == 0) sf[bid] = (red[0]+red[1]+red[2]+red[3]) * (1.0f/16384.0f);
  } else {
    // ---- qkv body (R2-verbatim) ----
    swq[tid] = wq[tid]; swk[tid] = wk[tid]; swv[tid] = wv[tid]; swo[tid] = wo[tid];
    if (tid < 16) { sbq[tid] = bq[tid]; sbk[tid] = bk[tid]; sbv[tid] = bv[tid]; }
    __syncthreads();
    int row = (blockIdx.x - 192) * 256 + tid;
    int idx = act[row];
    const float4* f4 = (const float4*)(feat + (size_t)idx * 16);
    float4 a0 = f4[0], a1 = f4[1], a2 = f4[2], a3 = f4[3];
    float af[16] = {a0.x,a0.y,a0.z,a0.w, a1.x,a1.y,a1.z,a1.w,
                    a2.x,a2.y,a2.z,a2.w, a3.x,a3.y,a3.z,a3.w};
    float q[16], k[16], v[16];
    #pragma unroll
    for (int kk = 0; kk < 16; ++kk) {
      float aq = sbq[kk], ak = sbk[kk], av = sbv[kk];
      #pragma unroll
      for (int f = 0; f < 16; ++f) {
        aq = fmaf(af[f], swq[f*16+kk], aq);
        ak = fmaf(af[f], swk[f*16+kk], ak);
        av = fmaf(af[f], swv[f*16+kk], av);
      }
      q[kk] = aq; k[kk] = ak; v[kk] = av;
    }
    const float qs = 0.25f * LOG2E;
    #pragma unroll
    for (int kk = 0; kk < 16; ++kk) {
      float a = 0.f;
      #pragma unroll
      for (int f = 0; f < 16; ++f) a = fmaf(v[f], swo[f*16+kk], a);
      V2T[(size_t)kk * A_N + row] = f2bf(a);
      Qo[(size_t)row*16 + kk] = f2bf(q[kk] * qs);
      Ko[(size_t)row*16 + kk] = f2bf(k[kk]);
    }
  }
}

// ---------------- K2: cvec (R2-verbatim) ------------------------------------------
__global__ void cvec_kernel(const float* __restrict__ sf, const float* __restrict__ w1,
                            const float* __restrict__ b1, const float* __restrict__ bo,
                            float* __restrict__ cvec) {
  int k = threadIdx.x;
  if (k >= 16) return;
  float c = b1[k];
  for (int s = 0; s < 192; ++s) c = fmaf(sf[s], w1[s*16+k], c);
  for (int f = 0; f < 16; ++f)  c = fmaf(bo[f], w1[(192+f)*16+k], c);
  cvec[k] = c;
}

// ---------------- K3: MFMA flash attention + fused MLP scoring (R2-VERBATIM) ------
__global__ __launch_bounds__(256) void attn_score(
    const short* __restrict__ Qb, const short* __restrict__ Kb,
    const short* __restrict__ V2T, const float* __restrict__ cvec,
    const float* __restrict__ w1, const float* __restrict__ w2,
    float* __restrict__ scores) {
  __shared__ float sacc[4][16][16];
  __shared__ float sl[4][16];
  __shared__ float sw1[256];
  __shared__ float scv[16], sw2s[16];
  int tid = threadIdx.x;
  sw1[tid] = w1[192*16 + tid];
  if (tid < 16) { scv[tid] = cvec[tid]; sw2s[tid] = w2[tid]; }
  int w = tid >> 6, lane = tid & 63;
  int g = lane >> 4, fi = lane & 15;
  int i0 = blockIdx.x * 16;

  short8v z8 = {};
  short8v qf = z8;
  if (g < 2) qf = *(const short8v*)(Qb + (size_t)(i0 + fi)*16 + g*8);
  const short* kp = Kb + (size_t)(w*2048 + fi)*16 + g*8;
  const short* vp = V2T + (size_t)fi*A_N + w*2048 + g*4;

  f32x4 acc = {0.f,0.f,0.f,0.f};
  float lsum = 0.f;
  #pragma unroll 2
  for (int step = 0; step < 64; ++step) {
    short8v kf0 = z8, kf1 = z8;
    if (g < 2) {
      kf0 = *(const short8v*)(kp);
      kf1 = *(const short8v*)(kp + 256);   // +16 rows
    }
    f32x4 zero4 = {0.f,0.f,0.f,0.f};
    f32x4 e0 = __builtin_amdgcn_mfma_f32_16x16x32_bf16(kf0, qf, zero4, 0, 0, 0);
    f32x4 e1 = __builtin_amdgcn_mfma_f32_16x16x32_bf16(kf1, qf, zero4, 0, 0, 0);
    float p00 = fexp2(e0[0]), p01 = fexp2(e0[1]), p02 = fexp2(e0[2]), p03 = fexp2(e0[3]);
    float p10 = fexp2(e1[0]), p11 = fexp2(e1[1]), p12 = fexp2(e1[2]), p13 = fexp2(e1[3]);
    lsum += ((p00+p01)+(p02+p03)) + ((p10+p11)+(p12+p13));
    i32x4 pk;
    pk[0] = cvtpk(p00, p01); pk[1] = cvtpk(p02, p03);
    pk[2] = cvtpk(p10, p11); pk[3] = cvtpk(p12, p13);
    short8v pa = __builtin_bit_cast(short8v, pk);
    int2 va = *(const int2*)(vp);
    int2 vb = *(const int2*)(vp + 16);   // +16 j
    i32x4 vv; vv[0] = va.x; vv[1] = va.y; vv[2] = vb.x; vv[3] = vb.y;
    short8v vf = __builtin_bit_cast(short8v, vv);
    acc = __builtin_amdgcn_mfma_f32_16x16x32_bf16(pa, vf, acc, 0, 0, 0);
    kp += 512;  // 32 rows * 16
    vp += 32;   // 32 j
  }
  lsum += __shfl_xor(lsum, 16, 64);
  lsum += __shfl_xor(lsum, 32, 64);
  #pragma unroll
  for (int r = 0; r < 4; ++r) sacc[w][4*g + r][fi] = acc[r];
  if (g == 0) sl[w][fi] = lsum;
  __syncthreads();
  {
    int i = tid >> 4, f = tid & 15;
    float o = sacc[0][i][f] + sacc[1][i][f] + sacc[2][i][f] + sacc[3][i][f];
    float li = sl[0][i] + sl[1][i] + sl[2][i] + sl[3][i];
    sacc[0][i][f] = o / li;
  }
  __syncthreads();
  {
    int i = tid >> 4, k = tid & 15;
    float h = scv[k];
    #pragma unroll
    for (int f = 0; f < 16; ++f) h = fmaf(sacc[0][i][f], sw1[f*16+k], h);
    h = fmaxf(h, 0.f);
    float t = h * sw2s[k];
    t += __shfl_xor(t, 1, 64);
    t += __shfl_xor(t, 2, 64);
    t += __shfl_xor(t, 4, 64);
    t += __shfl_xor(t, 8, 64);
    if (k == 0) scores[i0 + i] = t;
  }
}

// ---------------- K4: softmax over the 8192 scores (R2-verbatim) ------------------
__global__ __launch_bounds__(1024) void softmax_final(
    const float* __restrict__ scores, float* __restrict__ out) {
  __shared__ float red[16];
  __shared__ float sbc[2];
  int tid = threadIdx.x;
  int lane = tid & 63, wid = tid >> 6;
  float m = -3.4e38f;
  for (int i = tid; i < A_N; i += 1024) m = fmaxf(m, scores[i]);
  for (int o = 32; o; o >>= 1) m = fmaxf(m, __shfl_down(m, o, 64));
  if (lane == 0) red[wid] = m;
  __syncthreads();
  if (tid == 0) {
    float mm = red[0];
    for (int w = 1; w < 16; ++w) mm = fmaxf(mm, red[w]);
    sbc[0] = mm;
  }
  __syncthreads();
  float mx = sbc[0];
  float s = 0.f;
  for (int i = tid; i < A_N; i += 1024) s += __expf(scores[i] - mx);
  for (int o = 32; o; o >>= 1) s += __shfl_down(s, o, 64);
  if (lane == 0) red[wid] = s;
  __syncthreads();
  if (tid == 0) {
    float ss = 0.f;
    for (int w = 0; w < 16; ++w) ss += red[w];
    sbc[1] = ss;
  }
  __syncthreads();
  float inv = 1.0f / sbc[1];
  for (int i = tid; i < A_N; i += 1024) out[i] = __expf(scores[i] - mx) * inv;
}

extern "C" void kernel_launch(void* const* d_in, const int* in_sizes, int n_in,
                              void* d_out, int out_size, void* d_ws, size_t ws_size,
                              hipStream_t stream) {
  const float* x      = (const float*)d_in[0];
  const int*   act    = (const int*)  d_in[1];
  const float* feat   = (const float*)d_in[2];
  const float* conv_w = (const float*)d_in[3];
  const float* conv_b = (const float*)d_in[4];
  const float* wq     = (const float*)d_in[5];
  const float* bq     = (const float*)d_in[6];
  const float* wk     = (const float*)d_in[7];
  const float* bk     = (const float*)d_in[8];
  const float* wv     = (const float*)d_in[9];
  const float* bv     = (const float*)d_in[10];
  const float* wo     = (const float*)d_in[11];
  const float* bo     = (const float*)d_in[12];
  const float* w1     = (const float*)d_in[13];
  const float* b1     = (const float*)d_in[14];
  const float* w2     = (const float*)d_in[15];
  // d_in[16] = mlp_b2: softmax shift-invariant, dropped.

  char* wsb = (char*)d_ws;
  float* sf     = (float*)(wsb);             // 192 floats
  float* cvec   = (float*)(wsb + 1024);      // 16
  float* scores = (float*)(wsb + 2048);      // 8192
  short* Qb     = (short*)(wsb + 65536);             // 8192*16 bf16
  short* Kb     = (short*)(wsb + 65536 + 262144);    // 8192*16 bf16
  short* V2T    = (short*)(wsb + 65536 + 524288);    // 16*8192 bf16
  float* out    = (float*)d_out;

  fused_pre    <<<224, 256, 0, stream>>>(x, conv_w, conv_b, sf,
                                         act, feat, wq, bq, wk, bk, wv, bv, wo,
                                         Qb, Kb, V2T);
  cvec_kernel  <<<1, 64, 0, stream>>>(sf, w1, b1, bo, cvec);
  attn_score   <<<A_N/16, 256, 0, stream>>>(Qb, Kb, V2T, cvec, w1, w2, scores);
  softmax_final<<<1, 1024, 0, stream>>>(scores, out);
}